// Round 7
// baseline (920.069 us; speedup 1.0000x reference)
//
#include <hip/hip_runtime.h>
#include <hip/hip_bf16.h>
#include <math.h>

// Problem constants
#define B_SZ   8
#define SEQ    2048
#define DMODEL 512
#define DEPTH  2
#define DSTATE 16
#define DCONV  4
#define DINNER 1024
#define DTRANK 32
#define ROWS   (B_SZ * SEQ)          // 16384
#define DBCW   (DTRANK + 2 * DSTATE) // 64

typedef unsigned short u16;
typedef float f32x4 __attribute__((ext_vector_type(4)));
typedef short bf16x8 __attribute__((ext_vector_type(8)));

// Fast device math (native v_exp/v_log/v_rcp)
__device__ __forceinline__ float silu_f(float v) {
    return v * __builtin_amdgcn_rcpf(1.f + __expf(-v));
}
__device__ __forceinline__ float softplus_f(float s) {
    return (s > 20.f) ? s : __logf(1.f + __expf(s));
}
__device__ __forceinline__ u16 f2b(float v) {
    __hip_bfloat16 h = __float2bfloat16(v);
    return *(u16*)&h;
}
__device__ __forceinline__ float b2f(u16 v) {
    __hip_bfloat16 h;
    *(u16*)&h = v;
    return __bfloat162float(h);
}
// sum across the 16-lane state group (DPP row rotate-reduce; all 16 lanes end with the total)
__device__ __forceinline__ float sum16(float x) {
    x += __int_as_float(__builtin_amdgcn_update_dpp(0, __float_as_int(x), 0x121, 0xf, 0xf, true));
    x += __int_as_float(__builtin_amdgcn_update_dpp(0, __float_as_int(x), 0x122, 0xf, 0xf, true));
    x += __int_as_float(__builtin_amdgcn_update_dpp(0, __float_as_int(x), 0x124, 0xf, 0xf, true));
    x += __int_as_float(__builtin_amdgcn_update_dpp(0, __float_as_int(x), 0x128, 0xf, 0xf, true));
    return x;
}

__device__ __forceinline__ void load_lds16(const void* g, void* l) {
    __builtin_amdgcn_global_load_lds(
        (const __attribute__((address_space(1))) unsigned int*)g,
        (__attribute__((address_space(3))) unsigned int*)l, 16, 0, 0);
}

// ---------------------------------------------------------------- fused weight conversion (1 launch/layer)
#define N_INW  (2 * DINNER * DMODEL)   // 2,097,152
#define N_OUTW (DMODEL * DINNER)       // 1,048,576
#define N_XW   (DBCW * DINNER)         //    65,536
__global__ __launch_bounds__(256) void conv_weights(const float* __restrict__ iw,
                                                    const float* __restrict__ ow,
                                                    const float* __restrict__ xw,
                                                    u16* __restrict__ inwbf,
                                                    u16* __restrict__ outwbf,
                                                    u16* __restrict__ xwbf) {
    int i = blockIdx.x * 256 + threadIdx.x;
    if (i < N_INW) inwbf[i] = f2b(iw[i]);
    else if (i < N_INW + N_OUTW) outwbf[i - N_INW] = f2b(ow[i - N_INW]);
    else if (i < N_INW + N_OUTW + N_XW) xwbf[i - N_INW - N_OUTW] = f2b(xw[i - N_INW - N_OUTW]);
}

// ---------------------------------------------------------------- LayerNorm (bf16 out)
__global__ __launch_bounds__(256) void ln_kernel(const float* __restrict__ x,
                                                 const float* __restrict__ w,
                                                 const float* __restrict__ b,
                                                 u16* __restrict__ out) {
    int r = blockIdx.x;
    int tid = threadIdx.x;
    const float* xr = x + (size_t)r * DMODEL;
    float2 v = *(const float2*)(xr + tid * 2);
    float s = v.x + v.y;
    float s2 = v.x * v.x + v.y * v.y;
    #pragma unroll
    for (int off = 1; off < 64; off <<= 1) {
        s  += __shfl_xor(s, off);
        s2 += __shfl_xor(s2, off);
    }
    __shared__ float ws[4], ws2[4];
    int wid = tid >> 6, lane = tid & 63;
    if (lane == 0) { ws[wid] = s; ws2[wid] = s2; }
    __syncthreads();
    float ts = ws[0] + ws[1] + ws[2] + ws[3];
    float ts2 = ws2[0] + ws2[1] + ws2[2] + ws2[3];
    float mean = ts * (1.f / DMODEL);
    float var = ts2 * (1.f / DMODEL) - mean * mean;
    float inv = rsqrtf(var + 1e-5f);
    out[(size_t)r * DMODEL + tid * 2]     = f2b((v.x - mean) * inv * w[tid * 2] + b[tid * 2]);
    out[(size_t)r * DMODEL + tid * 2 + 1] = f2b((v.y - mean) * inv * w[tid * 2 + 1] + b[tid * 2 + 1]);
}

// ---------------------------------------------------------------- in_proj bf16 MFMA GEMM with TRANSPOSED epilogue
// Outputs directly in scan layout: xt[b,e,t] (xi half), szt[b,e,t] = silu(z) (z half).
// Tile 128r x 128c transposed through a 17 KB LDS buffer in two 64-col passes;
// stores are 64 B-contiguous per e-row (coalesced). This deletes u_t's transpose traffic.
__global__ __launch_bounds__(256) void gemm_in(const u16* __restrict__ A,
                                               const u16* __restrict__ W,
                                               u16* __restrict__ xt,
                                               u16* __restrict__ szt) {
    __shared__ u16 As[128 * 32];
    __shared__ u16 Bs[128 * 32];
    __shared__ u16 ts[64 * 136];    // 64 cols x 128 rows (+pad), 16B-aligned rows
    const int K = DMODEL;
    int tid = threadIdx.x;
    int wave = tid >> 6, lane = tid & 63;
    int wm = (wave >> 1) * 64, wn = (wave & 1) * 64;
    int m0 = blockIdx.y * 128, n0 = blockIdx.x * 128;
    int srow = lane >> 2, sseg = lane & 3;
    const u16* Ag = A + (size_t)(m0 + wave * 32 + srow) * K + sseg * 8;
    const u16* Wg = W + (size_t)(n0 + wave * 32 + srow) * K + sseg * 8;
    u16* Asw = As + wave * 32 * 32;
    u16* Bsw = Bs + wave * 32 * 32;

    f32x4 acc[4][4] = {};
    int col = lane & 15, quad = lane >> 4;

    for (int k0 = 0; k0 < K; k0 += 32) {
        __syncthreads();
        load_lds16(Ag + k0, Asw);
        load_lds16(Ag + k0 + (size_t)16 * K, Asw + 16 * 32);
        load_lds16(Wg + k0, Bsw);
        load_lds16(Wg + k0 + (size_t)16 * K, Bsw + 16 * 32);
        __syncthreads();
        bf16x8 af[4], bfr[4];
        #pragma unroll
        for (int i = 0; i < 4; ++i) {
            af[i]  = *(const bf16x8*)(As + (wm + i * 16 + col) * 32 + quad * 8);
            bfr[i] = *(const bf16x8*)(Bs + (wn + i * 16 + col) * 32 + quad * 8);
        }
        #pragma unroll
        for (int i = 0; i < 4; ++i)
            #pragma unroll
            for (int j = 0; j < 4; ++j)
                acc[i][j] = __builtin_amdgcn_mfma_f32_16x16x32_bf16(af[i], bfr[j], acc[i][j], 0, 0, 0);
    }

    bool is_z = (n0 >= DINNER);
    u16* dstT = is_z ? szt : xt;
    int nb = n0 & (DINNER - 1);
    int bb = m0 >> 11;              // m0 / SEQ
    int t0 = m0 & (SEQ - 1);

    // two passes: pass hp transposes the 64 cols owned by waves with (wave&1)==hp
    for (int hp = 0; hp < 2; ++hp) {
        __syncthreads();
        if ((wave & 1) == hp) {
            #pragma unroll
            for (int i = 0; i < 4; ++i)
                #pragma unroll
                for (int j = 0; j < 4; ++j)
                    #pragma unroll
                    for (int r = 0; r < 4; ++r) {
                        int row = wm + i * 16 + quad * 4 + r;   // t-local 0..127
                        int cl  = j * 16 + col;                  // e-local 0..63
                        float v = acc[i][j][r];
                        if (is_z) v = silu_f(v);
                        ts[cl * 136 + row] = f2b(v);
                    }
        }
        __syncthreads();
        int cl = tid >> 2, tp = tid & 3;                         // 64 e-rows x 4 t-quarters
        const u16* src = ts + cl * 136 + tp * 32;
        bf16x8 o0 = *(const bf16x8*)(src);
        bf16x8 o1 = *(const bf16x8*)(src + 8);
        bf16x8 o2 = *(const bf16x8*)(src + 16);
        bf16x8 o3 = *(const bf16x8*)(src + 24);
        u16* d = dstT + ((size_t)bb * DINNER + nb + hp * 64 + cl) * SEQ + t0 + tp * 32;
        *(bf16x8*)(d)      = o0;
        *(bf16x8*)(d + 8)  = o1;
        *(bf16x8*)(d + 16) = o2;
        *(bf16x8*)(d + 24) = o3;
    }
}

// ---------------------------------------------------------------- out_proj bf16 MFMA GEMM (+residual, fp32 out)
__global__ __launch_bounds__(256) void gemm_out(const u16* __restrict__ A,
                                                const u16* __restrict__ W,
                                                const float* __restrict__ res,
                                                float* __restrict__ C) {
    __shared__ u16 As[128 * 32];
    __shared__ u16 Bs[128 * 32];
    const int K = DINNER, N = DMODEL;
    int tid = threadIdx.x;
    int wave = tid >> 6, lane = tid & 63;
    int wm = (wave >> 1) * 64, wn = (wave & 1) * 64;
    int m0 = blockIdx.y * 128, n0 = blockIdx.x * 128;
    int srow = lane >> 2, sseg = lane & 3;
    const u16* Ag = A + (size_t)(m0 + wave * 32 + srow) * K + sseg * 8;
    const u16* Wg = W + (size_t)(n0 + wave * 32 + srow) * K + sseg * 8;
    u16* Asw = As + wave * 32 * 32;
    u16* Bsw = Bs + wave * 32 * 32;

    f32x4 acc[4][4] = {};
    int col = lane & 15, quad = lane >> 4;

    for (int k0 = 0; k0 < K; k0 += 32) {
        __syncthreads();
        load_lds16(Ag + k0, Asw);
        load_lds16(Ag + k0 + (size_t)16 * K, Asw + 16 * 32);
        load_lds16(Wg + k0, Bsw);
        load_lds16(Wg + k0 + (size_t)16 * K, Bsw + 16 * 32);
        __syncthreads();
        bf16x8 af[4], bfr[4];
        #pragma unroll
        for (int i = 0; i < 4; ++i) {
            af[i]  = *(const bf16x8*)(As + (wm + i * 16 + col) * 32 + quad * 8);
            bfr[i] = *(const bf16x8*)(Bs + (wn + i * 16 + col) * 32 + quad * 8);
        }
        #pragma unroll
        for (int i = 0; i < 4; ++i)
            #pragma unroll
            for (int j = 0; j < 4; ++j)
                acc[i][j] = __builtin_amdgcn_mfma_f32_16x16x32_bf16(af[i], bfr[j], acc[i][j], 0, 0, 0);
    }
    #pragma unroll
    for (int i = 0; i < 4; ++i) {
        int gm_base = m0 + wm + i * 16 + quad * 4;
        #pragma unroll
        for (int j = 0; j < 4; ++j) {
            int gn = n0 + wn + j * 16 + col;
            #pragma unroll
            for (int r = 0; r < 4; ++r) {
                size_t off = (size_t)(gm_base + r) * N + gn;
                C[off] = acc[i][j][r] + res[off];
            }
        }
    }
}

// ---------------------------------------------------------------- x_proj bf16 MFMA GEMM (N=64)
__global__ __launch_bounds__(256) void gemm_xp_bf16(const u16* __restrict__ A,
                                                    const u16* __restrict__ W,
                                                    float* __restrict__ C) {
    __shared__ u16 As[128 * 32];
    __shared__ u16 Bs[64 * 32];
    int tid = threadIdx.x;
    int wave = tid >> 6, lane = tid & 63;
    int m0 = blockIdx.x * 128;
    int wm = wave * 32;
    int srow = lane >> 2, sseg = lane & 3;
    const u16* Ag = A + (size_t)(m0 + wm + srow) * DINNER + sseg * 8;
    const u16* Wg = W + (size_t)(wave * 16 + srow) * DINNER + sseg * 8;
    u16* Asw = As + wave * 32 * 32;
    u16* Bsw = Bs + wave * 16 * 32;

    f32x4 acc[2][4] = {};
    int col = lane & 15, quad = lane >> 4;

    for (int k0 = 0; k0 < DINNER; k0 += 32) {
        __syncthreads();
        load_lds16(Ag + k0, Asw);
        load_lds16(Ag + k0 + (size_t)16 * DINNER, Asw + 16 * 32);
        load_lds16(Wg + k0, Bsw);
        __syncthreads();
        bf16x8 af[2], bfr[4];
        #pragma unroll
        for (int i = 0; i < 2; ++i)
            af[i] = *(const bf16x8*)(As + (wm + i * 16 + col) * 32 + quad * 8);
        #pragma unroll
        for (int j = 0; j < 4; ++j)
            bfr[j] = *(const bf16x8*)(Bs + (j * 16 + col) * 32 + quad * 8);
        #pragma unroll
        for (int i = 0; i < 2; ++i)
            #pragma unroll
            for (int j = 0; j < 4; ++j)
                acc[i][j] = __builtin_amdgcn_mfma_f32_16x16x32_bf16(af[i], bfr[j], acc[i][j], 0, 0, 0);
    }
    #pragma unroll
    for (int i = 0; i < 2; ++i) {
        int gm_base = m0 + wm + i * 16 + quad * 4;
        #pragma unroll
        for (int j = 0; j < 4; ++j) {
            int gn = j * 16 + col;
            #pragma unroll
            for (int r = 0; r < 4; ++r)
                C[(size_t)(gm_base + r) * DBCW + gn] = acc[i][j][r];
        }
    }
}

// ---------------------------------------------------------------- u precompute from xt[b,e,t] (no input transpose, no sz)
// Thread (e, tg): slides the 4-tap conv along 16 contiguous t from 3 vector loads.
// Writes ut[b,e,t] contiguous (2x16B) + u_re[r,e] via LDS transpose (for gemm_xp).
__global__ __launch_bounds__(256) void u_t_kernel(const u16* __restrict__ xt,
                                                  const float* __restrict__ cw,
                                                  const float* __restrict__ cb,
                                                  u16* __restrict__ ut,
                                                  u16* __restrict__ u_re) {
    __shared__ u16 uo[64][70];
    int tid = threadIdx.x;
    int t0 = blockIdx.x * 64, e0 = blockIdx.y * 64, b = blockIdx.z;
    int el = tid & 63, tg = tid >> 6;
    int e = e0 + el;
    int tbase = t0 + tg * 16;
    const u16* row = xt + ((size_t)b * DINNER + e) * SEQ;
    bf16x8 s0, s1, s2;
    if (tbase >= 8) s0 = *(const bf16x8*)(row + tbase - 8);
    else            s0 = (bf16x8){0, 0, 0, 0, 0, 0, 0, 0};
    s1 = *(const bf16x8*)(row + tbase);
    s2 = *(const bf16x8*)(row + tbase + 8);
    float4 w4 = *(const float4*)(cw + e * 4);
    float cbe = cb[e];
    float x3 = b2f((u16)s0[5]), x2 = b2f((u16)s0[6]), x1 = b2f((u16)s0[7]);
    bf16x8 o0, o1;
    #pragma unroll
    for (int i = 0; i < 16; ++i) {
        float x0 = b2f((u16)((i < 8) ? s1[i] : s2[i - 8]));
        float u = silu_f(cbe + w4.x * x3 + w4.y * x2 + w4.z * x1 + w4.w * x0);
        x3 = x2; x2 = x1; x1 = x0;
        u16 ub = f2b(u);
        if (i < 8) o0[i] = (short)ub; else o1[i - 8] = (short)ub;
        uo[el][tg * 16 + i] = ub;
    }
    u16* ud = ut + ((size_t)b * DINNER + e) * SEQ + tbase;
    *(bf16x8*)(ud)     = o0;
    *(bf16x8*)(ud + 8) = o1;
    __syncthreads();
    {
        int tl = tid & 63, eg = tid >> 6;
        #pragma unroll
        for (int i = 0; i < 16; ++i) {
            int ee = eg * 16 + i;
            u_re[((size_t)b * SEQ + t0 + tl) * DINNER + e0 + ee] = uo[ee][tl];
        }
    }
}

// ---------------------------------------------------------------- delta + B/C precompute (round-0 proven)
__global__ __launch_bounds__(256) void delta_bct_kernel(const float* __restrict__ dbc,
                                                        const float* __restrict__ dtw,
                                                        const float* __restrict__ dtb,
                                                        u16* __restrict__ dlt,
                                                        u16* __restrict__ Bt,
                                                        u16* __restrict__ Ct) {
    __shared__ float wl[64 * 32];
    __shared__ float bl[64];
    int tid = threadIdx.x;
    int e0 = blockIdx.x * 64, t0 = blockIdx.y * 256, b = blockIdx.z;
    for (int i = tid; i < 64 * 32; i += 256) wl[i] = dtw[(size_t)e0 * DTRANK + i];
    if (tid < 64) bl[tid] = dtb[e0 + tid];
    float dreg[32];
    const float* dp = dbc + (size_t)(b * SEQ + t0 + tid) * DBCW;
    #pragma unroll
    for (int k = 0; k < 32; k += 4) {
        float4 v = *(const float4*)(dp + k);
        dreg[k] = v.x; dreg[k + 1] = v.y; dreg[k + 2] = v.z; dreg[k + 3] = v.w;
    }
    __syncthreads();
    for (int ep = 0; ep < 64; ++ep) {
        float s = bl[ep];
        #pragma unroll
        for (int k = 0; k < 32; ++k) s += dreg[k] * wl[ep * 32 + k];
        dlt[((size_t)b * DINNER + e0 + ep) * SEQ + t0 + tid] = f2b(softplus_f(s));
    }
    if (blockIdx.x == 0) {
        int t = t0 + tid;
        const float* dp2 = dbc + (size_t)(b * SEQ + t) * DBCW + DTRANK;
        #pragma unroll
        for (int nn = 0; nn < DSTATE; ++nn) {
            Bt[((size_t)b * DSTATE + nn) * SEQ + t] = f2b(dp2[nn]);
            Ct[((size_t)b * DSTATE + nn) * SEQ + t] = f2b(dp2[DSTATE + nn]);
        }
    }
}

// ---------------------------------------------------------------- selective scan (round-4 pipelined version, unchanged)
#define SCHUNK 16

struct ChunkBuf {
    bf16x8 u0, u1, d0, d1, b0, b1, c0, c1;
    u16 uo_r, szo_r;
};

__global__ __launch_bounds__(256, 2) void scan_fused(u16* __restrict__ y_re,
                                                     const u16* __restrict__ ut,
                                                     const u16* __restrict__ dlt,
                                                     const u16* __restrict__ Bt,
                                                     const u16* __restrict__ Ct,
                                                     const u16* __restrict__ szt,
                                                     const float* __restrict__ Alog,
                                                     const float* __restrict__ Dp) {
    int tid = threadIdx.x;
    int pair = tid >> 4, n = tid & 15;
    int blk = blockIdx.x;
    int b = blk >> 6;
    int e = ((blk & 63) << 4) + pair;
    float a2 = -__expf(Alog[e * DSTATE + n]) * 1.44269504f;   // fold log2e: dA = exp2(dl*a2)
    float dpe = Dp[e];
    const u16* urow  = ut  + ((size_t)b * DINNER + e) * SEQ;
    const u16* dlrow = dlt + ((size_t)b * DINNER + e) * SEQ;
    const u16* szrow = szt + ((size_t)b * DINNER + e) * SEQ;
    const u16* Brow  = Bt + ((size_t)b * DSTATE + n) * SEQ;
    const u16* Crow  = Ct + ((size_t)b * DSTATE + n) * SEQ;
    // lane n stores t = c*16+n for its pair: scatter over 16 rows
    u16* ystore = y_re + ((size_t)b * SEQ + n) * DINNER + e;

    // per-lane 0/1 mask: lane n keeps time-step j==n of each chunk (1 fma/t)
    float msk[16];
    #pragma unroll
    for (int j = 0; j < 16; ++j) msk[j] = (n == j) ? 1.f : 0.f;

    float h = 0.f;
    ChunkBuf bufA, bufB, bufC, bufD;

    auto load = [&](int c, ChunkBuf& R) {
        R.u0 = *(const bf16x8*)(urow + c * SCHUNK);
        R.u1 = *(const bf16x8*)(urow + c * SCHUNK + 8);
        R.d0 = *(const bf16x8*)(dlrow + c * SCHUNK);
        R.d1 = *(const bf16x8*)(dlrow + c * SCHUNK + 8);
        R.b0 = *(const bf16x8*)(Brow + c * SCHUNK);
        R.b1 = *(const bf16x8*)(Brow + c * SCHUNK + 8);
        R.c0 = *(const bf16x8*)(Crow + c * SCHUNK);
        R.c1 = *(const bf16x8*)(Crow + c * SCHUNK + 8);
        R.uo_r  = urow[c * SCHUNK + n];    // lane n's own t (same cacheline as u0/u1)
        R.szo_r = szrow[c * SCHUNK + n];
    };
    auto proc = [&](int c, const ChunkBuf& R) {
        float keep = 0.f;
        #pragma unroll
        for (int j = 0; j < SCHUNK; ++j) {
            float uf = b2f((u16)((j < 8) ? R.u0[j] : R.u1[j - 8]));
            float dl = b2f((u16)((j < 8) ? R.d0[j] : R.d1[j - 8]));
            float dA = __builtin_amdgcn_exp2f(dl * a2);
            h = dA * h + (dl * uf) * b2f((u16)((j < 8) ? R.b0[j] : R.b1[j - 8]));
            float yp = sum16(h * b2f((u16)((j < 8) ? R.c0[j] : R.c1[j - 8])));
            keep += yp * msk[j];   // lane n keeps its own t's value
        }
        ystore[(size_t)c * SCHUNK * DINNER] =
            f2b((keep + b2f(R.uo_r) * dpe) * b2f(R.szo_r));
    };

    const int nc = SEQ / SCHUNK;   // 128, divisible by 4
    load(0, bufA);
    load(1, bufB);
    load(2, bufC);
    __builtin_amdgcn_sched_barrier(0);
    for (int c = 0; c < nc; c += 4) {
        int c3 = c + 3, c4 = c + 4, c5 = c + 5, c6 = c + 6;
        c4 = (c4 < nc) ? c4 : nc - 1;   // tail: redundant reloads of last chunk (cheap, branch-free)
        c5 = (c5 < nc) ? c5 : nc - 1;
        c6 = (c6 < nc) ? c6 : nc - 1;
        load(c3, bufD);  __builtin_amdgcn_sched_barrier(0);  proc(c,     bufA);
        load(c4, bufA);  __builtin_amdgcn_sched_barrier(0);  proc(c + 1, bufB);
        load(c5, bufB);  __builtin_amdgcn_sched_barrier(0);  proc(c + 2, bufC);
        load(c6, bufC);  __builtin_amdgcn_sched_barrier(0);  proc(c + 3, bufD);
    }
}

// ---------------------------------------------------------------- launch
extern "C" void kernel_launch(void* const* d_in, const int* in_sizes, int n_in,
                              void* d_out, int out_size, void* d_ws, size_t ws_size,
                              hipStream_t stream) {
    const float* x_in   = (const float*)d_in[0];
    const float* ln_w   = (const float*)d_in[1];
    const float* ln_b   = (const float*)d_in[2];
    const float* inw    = (const float*)d_in[3];
    const float* convw  = (const float*)d_in[4];
    const float* convb  = (const float*)d_in[5];
    const float* xpw    = (const float*)d_in[6];
    const float* dtw    = (const float*)d_in[7];
    const float* dtb    = (const float*)d_in[8];
    const float* Alog   = (const float*)d_in[9];
    const float* Dp     = (const float*)d_in[10];
    const float* outw   = (const float*)d_in[11];
    float* out = (float*)d_out;

    // workspace carve-up — same proven footprint; xi_re/sz_re regions now hold the
    // TRANSPOSED xt/szt [b,e,t] written directly by gemm_in's epilogue.
    char* p = (char*)d_ws;
    u16* xt    = (u16*)p;               p += (size_t)ROWS * DINNER * 2;          //  33,554,432
    u16* szt   = (u16*)p;               p += (size_t)ROWS * DINNER * 2;          //  33,554,432
    u16* y_re  = (u16*)p;               p += (size_t)ROWS * DINNER * 2;          //  33,554,432
    float* dbc = (float*)p;             p += (size_t)ROWS * DBCW * 4;            //   4,194,304
    u16* dlt   = (u16*)p;               p += (size_t)B_SZ * DINNER * SEQ * 2;    //  33,554,432
    u16* u_re  = dlt;                   // alias: u_re consumed by gemm_xp before delta writes dlt
    u16* Bt    = (u16*)p;               p += (size_t)B_SZ * DSTATE * SEQ * 2;    //     524,288
    u16* xwbf  = Bt;                    // alias: xwbf consumed by gemm_xp before delta_bct writes Bt
    u16* Ct    = (u16*)p;               p += (size_t)B_SZ * DSTATE * SEQ * 2;    //     524,288
    u16* ut    = (u16*)p;               p += (size_t)B_SZ * DINNER * SEQ * 2;    //  33,554,432
    u16* xnbf  = ut;                    // alias: LN output (16.8 MB) dead before u_t writes ut
    u16* spare = (u16*)p;               p += (size_t)B_SZ * DINNER * SEQ * 2;    //  33,554,432 (unused)
    (void)spare;
    u16* inwbf = (u16*)p;               p += (size_t)N_INW * 2;                  //   4,194,304
    u16* outwbf = (u16*)p;              p += (size_t)N_OUTW * 2;                 //   2,097,152

    const dim3 blk256(256);
    const int n_conv = N_INW + N_OUTW + N_XW;

    for (int i = 0; i < DEPTH; ++i) {
        const float* x_cur = (i == 0) ? x_in : out;
        const float* lw  = ln_w  + (size_t)i * DMODEL;
        const float* lb  = ln_b  + (size_t)i * DMODEL;
        const float* iw  = inw   + (size_t)i * 2 * DINNER * DMODEL;
        const float* cw  = convw + (size_t)i * DINNER * DCONV;
        const float* cb  = convb + (size_t)i * DINNER;
        const float* xw  = xpw   + (size_t)i * DBCW * DINNER;
        const float* dw  = dtw   + (size_t)i * DINNER * DTRANK;
        const float* db  = dtb   + (size_t)i * DINNER;
        const float* Al  = Alog  + (size_t)i * DINNER * DSTATE;
        const float* Dpp = Dp    + (size_t)i * DINNER;
        const float* ow  = outw  + (size_t)i * DMODEL * DINNER;

        // 0. all weight conversions in one launch (xwbf parked in Bt region)
        conv_weights<<<(n_conv + 255) / 256, blk256, 0, stream>>>(
            iw, ow, xw, inwbf, outwbf, xwbf);
        // 1. LayerNorm -> bf16 (into ut region; dead before u_t writes)
        ln_kernel<<<ROWS, blk256, 0, stream>>>(x_cur, lw, lb, xnbf);
        // 2. in_proj (bf16 MFMA) with transposed epilogue: xt[b,e,t], szt[b,e,t]=silu(z)
        gemm_in<<<dim3(2 * DINNER / 128, ROWS / 128), blk256, 0, stream>>>(
            xnbf, inwbf, xt, szt);
        // 3. u precompute: ut[b,e,t] (contiguous) + u_re[r,e] (for gemm_xp)
        u_t_kernel<<<dim3(SEQ / 64, DINNER / 64, B_SZ), blk256, 0, stream>>>(
            xt, cw, cb, ut, u_re);
        // 4. x_proj (bf16 MFMA, N=64): dbc = u_re @ xw^T
        gemm_xp_bf16<<<ROWS / 128, blk256, 0, stream>>>(u_re, xwbf, dbc);
        // 5. delta + B/C precompute (overwrites u_re/xwbf regions, now dead)
        delta_bct_kernel<<<dim3(DINNER / 64, SEQ / 256, B_SZ), blk256, 0, stream>>>(
            dbc, dw, db, dlt, Bt, Ct);
        // 6. scan + register-keep gated output: y_re bf16
        scan_fused<<<(B_SZ * DINNER) / 16, blk256, 0, stream>>>(
            y_re, ut, dlt, Bt, Ct, szt, Al, Dpp);
        // 7. out_proj (bf16 MFMA) + residual
        gemm_out<<<dim3(DMODEL / 128, ROWS / 128), blk256, 0, stream>>>(
            y_re, outwbf, x_cur, out);
    }
}

// Round 9
// 841.783 us; speedup vs baseline: 1.0930x; 1.0930x over previous
//
#include <hip/hip_runtime.h>
#include <hip/hip_bf16.h>
#include <math.h>

// Problem constants
#define B_SZ   8
#define SEQ    2048
#define DMODEL 512
#define DEPTH  2
#define DSTATE 16
#define DCONV  4
#define DINNER 1024
#define DTRANK 32
#define ROWS   (B_SZ * SEQ)          // 16384
#define DBCW   (DTRANK + 2 * DSTATE) // 64

typedef unsigned short u16;
typedef float f32x4 __attribute__((ext_vector_type(4)));
typedef short bf16x8 __attribute__((ext_vector_type(8)));

// Fast device math (native v_exp/v_log/v_rcp)
__device__ __forceinline__ float silu_f(float v) {
    return v * __builtin_amdgcn_rcpf(1.f + __expf(-v));
}
__device__ __forceinline__ float softplus_f(float s) {
    return (s > 20.f) ? s : __logf(1.f + __expf(s));
}
__device__ __forceinline__ u16 f2b(float v) {
    __hip_bfloat16 h = __float2bfloat16(v);
    return *(u16*)&h;
}
__device__ __forceinline__ float b2f(u16 v) {
    __hip_bfloat16 h;
    *(u16*)&h = v;
    return __bfloat162float(h);
}
// sum across the 16-lane state group (DPP row rotate-reduce; all 16 lanes end with the total)
__device__ __forceinline__ float sum16(float x) {
    x += __int_as_float(__builtin_amdgcn_update_dpp(0, __float_as_int(x), 0x121, 0xf, 0xf, true));
    x += __int_as_float(__builtin_amdgcn_update_dpp(0, __float_as_int(x), 0x122, 0xf, 0xf, true));
    x += __int_as_float(__builtin_amdgcn_update_dpp(0, __float_as_int(x), 0x124, 0xf, 0xf, true));
    x += __int_as_float(__builtin_amdgcn_update_dpp(0, __float_as_int(x), 0x128, 0xf, 0xf, true));
    return x;
}

__device__ __forceinline__ void load_lds16(const void* g, void* l) {
    __builtin_amdgcn_global_load_lds(
        (const __attribute__((address_space(1))) unsigned int*)g,
        (__attribute__((address_space(3))) unsigned int*)l, 16, 0, 0);
}

// ---------------------------------------------------------------- fused weight conversion (1 launch/layer)
#define N_INW  (2 * DINNER * DMODEL)   // 2,097,152
#define N_OUTW (DMODEL * DINNER)       // 1,048,576
#define N_XW   (DBCW * DINNER)         //    65,536
__global__ __launch_bounds__(256) void conv_weights(const float* __restrict__ iw,
                                                    const float* __restrict__ ow,
                                                    const float* __restrict__ xw,
                                                    u16* __restrict__ inwbf,
                                                    u16* __restrict__ outwbf,
                                                    u16* __restrict__ xwbf) {
    int i = blockIdx.x * 256 + threadIdx.x;
    if (i < N_INW) inwbf[i] = f2b(iw[i]);
    else if (i < N_INW + N_OUTW) outwbf[i - N_INW] = f2b(ow[i - N_INW]);
    else if (i < N_INW + N_OUTW + N_XW) xwbf[i - N_INW - N_OUTW] = f2b(xw[i - N_INW - N_OUTW]);
}

// ---------------------------------------------------------------- LayerNorm (bf16 out)
__global__ __launch_bounds__(256) void ln_kernel(const float* __restrict__ x,
                                                 const float* __restrict__ w,
                                                 const float* __restrict__ b,
                                                 u16* __restrict__ out) {
    int r = blockIdx.x;
    int tid = threadIdx.x;
    const float* xr = x + (size_t)r * DMODEL;
    float2 v = *(const float2*)(xr + tid * 2);
    float s = v.x + v.y;
    float s2 = v.x * v.x + v.y * v.y;
    #pragma unroll
    for (int off = 1; off < 64; off <<= 1) {
        s  += __shfl_xor(s, off);
        s2 += __shfl_xor(s2, off);
    }
    __shared__ float ws[4], ws2[4];
    int wid = tid >> 6, lane = tid & 63;
    if (lane == 0) { ws[wid] = s; ws2[wid] = s2; }
    __syncthreads();
    float ts = ws[0] + ws[1] + ws[2] + ws[3];
    float ts2 = ws2[0] + ws2[1] + ws2[2] + ws2[3];
    float mean = ts * (1.f / DMODEL);
    float var = ts2 * (1.f / DMODEL) - mean * mean;
    float inv = rsqrtf(var + 1e-5f);
    out[(size_t)r * DMODEL + tid * 2]     = f2b((v.x - mean) * inv * w[tid * 2] + b[tid * 2]);
    out[(size_t)r * DMODEL + tid * 2 + 1] = f2b((v.y - mean) * inv * w[tid * 2 + 1] + b[tid * 2 + 1]);
}

// ---------------------------------------------------------------- in_proj bf16 MFMA GEMM
// x-half: row-major xi_re[r,e] (round-4 proven epilogue; u_t reads it e-major coalesced).
// z-half: silu + LDS-transposed epilogue -> szt[b,e,t] directly (deletes u_t's sz path).
__global__ __launch_bounds__(256) void gemm_in(const u16* __restrict__ A,
                                               const u16* __restrict__ W,
                                               u16* __restrict__ xi_re,
                                               u16* __restrict__ szt) {
    __shared__ u16 As[128 * 32];
    __shared__ u16 Bs[128 * 32];
    __shared__ u16 ts[64 * 136];    // z-half transpose staging: 64 cols x 128 rows (+pad)
    const int K = DMODEL;
    int tid = threadIdx.x;
    int wave = tid >> 6, lane = tid & 63;
    int wm = (wave >> 1) * 64, wn = (wave & 1) * 64;
    int m0 = blockIdx.y * 128, n0 = blockIdx.x * 128;
    int srow = lane >> 2, sseg = lane & 3;
    const u16* Ag = A + (size_t)(m0 + wave * 32 + srow) * K + sseg * 8;
    const u16* Wg = W + (size_t)(n0 + wave * 32 + srow) * K + sseg * 8;
    u16* Asw = As + wave * 32 * 32;
    u16* Bsw = Bs + wave * 32 * 32;

    f32x4 acc[4][4] = {};
    int col = lane & 15, quad = lane >> 4;

    for (int k0 = 0; k0 < K; k0 += 32) {
        __syncthreads();
        load_lds16(Ag + k0, Asw);
        load_lds16(Ag + k0 + (size_t)16 * K, Asw + 16 * 32);
        load_lds16(Wg + k0, Bsw);
        load_lds16(Wg + k0 + (size_t)16 * K, Bsw + 16 * 32);
        __syncthreads();
        bf16x8 af[4], bfr[4];
        #pragma unroll
        for (int i = 0; i < 4; ++i) {
            af[i]  = *(const bf16x8*)(As + (wm + i * 16 + col) * 32 + quad * 8);
            bfr[i] = *(const bf16x8*)(Bs + (wn + i * 16 + col) * 32 + quad * 8);
        }
        #pragma unroll
        for (int i = 0; i < 4; ++i)
            #pragma unroll
            for (int j = 0; j < 4; ++j)
                acc[i][j] = __builtin_amdgcn_mfma_f32_16x16x32_bf16(af[i], bfr[j], acc[i][j], 0, 0, 0);
    }

    if (n0 < DINNER) {
        // ---- x half: row-major xi_re (proven round-4 epilogue) ----
        #pragma unroll
        for (int i = 0; i < 4; ++i) {
            int gm_base = m0 + wm + i * 16 + quad * 4;
            #pragma unroll
            for (int j = 0; j < 4; ++j) {
                int gn = n0 + wn + j * 16 + col;
                #pragma unroll
                for (int r = 0; r < 4; ++r)
                    xi_re[(size_t)(gm_base + r) * DINNER + gn] = f2b(acc[i][j][r]);
            }
        }
    } else {
        // ---- z half: silu + LDS transpose -> szt[b,e,t] (proven round-7 epilogue) ----
        int nb = n0 & (DINNER - 1);
        int bb = m0 >> 11;              // m0 / SEQ
        int t0 = m0 & (SEQ - 1);
        for (int hp = 0; hp < 2; ++hp) {
            __syncthreads();
            if ((wave & 1) == hp) {
                #pragma unroll
                for (int i = 0; i < 4; ++i)
                    #pragma unroll
                    for (int j = 0; j < 4; ++j)
                        #pragma unroll
                        for (int r = 0; r < 4; ++r) {
                            int row = wm + i * 16 + quad * 4 + r;   // t-local 0..127
                            int cl  = j * 16 + col;                  // e-local 0..63
                            ts[cl * 136 + row] = f2b(silu_f(acc[i][j][r]));
                        }
            }
            __syncthreads();
            int cl = tid >> 2, tp = tid & 3;                         // 64 e-rows x 4 t-quarters
            const u16* src = ts + cl * 136 + tp * 32;
            bf16x8 o0 = *(const bf16x8*)(src);
            bf16x8 o1 = *(const bf16x8*)(src + 8);
            bf16x8 o2 = *(const bf16x8*)(src + 16);
            bf16x8 o3 = *(const bf16x8*)(src + 24);
            u16* d = szt + ((size_t)bb * DINNER + nb + hp * 64 + cl) * SEQ + t0 + tp * 32;
            *(bf16x8*)(d)      = o0;
            *(bf16x8*)(d + 8)  = o1;
            *(bf16x8*)(d + 16) = o2;
            *(bf16x8*)(d + 24) = o3;
        }
    }
}

// ---------------------------------------------------------------- out_proj bf16 MFMA GEMM (+residual, fp32 out)
__global__ __launch_bounds__(256) void gemm_out(const u16* __restrict__ A,
                                                const u16* __restrict__ W,
                                                const float* __restrict__ res,
                                                float* __restrict__ C) {
    __shared__ u16 As[128 * 32];
    __shared__ u16 Bs[128 * 32];
    const int K = DINNER, N = DMODEL;
    int tid = threadIdx.x;
    int wave = tid >> 6, lane = tid & 63;
    int wm = (wave >> 1) * 64, wn = (wave & 1) * 64;
    int m0 = blockIdx.y * 128, n0 = blockIdx.x * 128;
    int srow = lane >> 2, sseg = lane & 3;
    const u16* Ag = A + (size_t)(m0 + wave * 32 + srow) * K + sseg * 8;
    const u16* Wg = W + (size_t)(n0 + wave * 32 + srow) * K + sseg * 8;
    u16* Asw = As + wave * 32 * 32;
    u16* Bsw = Bs + wave * 32 * 32;

    f32x4 acc[4][4] = {};
    int col = lane & 15, quad = lane >> 4;

    for (int k0 = 0; k0 < K; k0 += 32) {
        __syncthreads();
        load_lds16(Ag + k0, Asw);
        load_lds16(Ag + k0 + (size_t)16 * K, Asw + 16 * 32);
        load_lds16(Wg + k0, Bsw);
        load_lds16(Wg + k0 + (size_t)16 * K, Bsw + 16 * 32);
        __syncthreads();
        bf16x8 af[4], bfr[4];
        #pragma unroll
        for (int i = 0; i < 4; ++i) {
            af[i]  = *(const bf16x8*)(As + (wm + i * 16 + col) * 32 + quad * 8);
            bfr[i] = *(const bf16x8*)(Bs + (wn + i * 16 + col) * 32 + quad * 8);
        }
        #pragma unroll
        for (int i = 0; i < 4; ++i)
            #pragma unroll
            for (int j = 0; j < 4; ++j)
                acc[i][j] = __builtin_amdgcn_mfma_f32_16x16x32_bf16(af[i], bfr[j], acc[i][j], 0, 0, 0);
    }
    #pragma unroll
    for (int i = 0; i < 4; ++i) {
        int gm_base = m0 + wm + i * 16 + quad * 4;
        #pragma unroll
        for (int j = 0; j < 4; ++j) {
            int gn = n0 + wn + j * 16 + col;
            #pragma unroll
            for (int r = 0; r < 4; ++r) {
                size_t off = (size_t)(gm_base + r) * N + gn;
                C[off] = acc[i][j][r] + res[off];
            }
        }
    }
}

// ---------------------------------------------------------------- x_proj bf16 MFMA GEMM (N=64)
__global__ __launch_bounds__(256) void gemm_xp_bf16(const u16* __restrict__ A,
                                                    const u16* __restrict__ W,
                                                    float* __restrict__ C) {
    __shared__ u16 As[128 * 32];
    __shared__ u16 Bs[64 * 32];
    int tid = threadIdx.x;
    int wave = tid >> 6, lane = tid & 63;
    int m0 = blockIdx.x * 128;
    int wm = wave * 32;
    int srow = lane >> 2, sseg = lane & 3;
    const u16* Ag = A + (size_t)(m0 + wm + srow) * DINNER + sseg * 8;
    const u16* Wg = W + (size_t)(wave * 16 + srow) * DINNER + sseg * 8;
    u16* Asw = As + wave * 32 * 32;
    u16* Bsw = Bs + wave * 16 * 32;

    f32x4 acc[2][4] = {};
    int col = lane & 15, quad = lane >> 4;

    for (int k0 = 0; k0 < DINNER; k0 += 32) {
        __syncthreads();
        load_lds16(Ag + k0, Asw);
        load_lds16(Ag + k0 + (size_t)16 * DINNER, Asw + 16 * 32);
        load_lds16(Wg + k0, Bsw);
        __syncthreads();
        bf16x8 af[2], bfr[4];
        #pragma unroll
        for (int i = 0; i < 2; ++i)
            af[i] = *(const bf16x8*)(As + (wm + i * 16 + col) * 32 + quad * 8);
        #pragma unroll
        for (int j = 0; j < 4; ++j)
            bfr[j] = *(const bf16x8*)(Bs + (j * 16 + col) * 32 + quad * 8);
        #pragma unroll
        for (int i = 0; i < 2; ++i)
            #pragma unroll
            for (int j = 0; j < 4; ++j)
                acc[i][j] = __builtin_amdgcn_mfma_f32_16x16x32_bf16(af[i], bfr[j], acc[i][j], 0, 0, 0);
    }
    #pragma unroll
    for (int i = 0; i < 2; ++i) {
        int gm_base = m0 + wm + i * 16 + quad * 4;
        #pragma unroll
        for (int j = 0; j < 4; ++j) {
            int gn = j * 16 + col;
            #pragma unroll
            for (int r = 0; r < 4; ++r)
                C[(size_t)(gm_base + r) * DBCW + gn] = acc[i][j][r];
        }
    }
}

// ---------------------------------------------------------------- u precompute (round-4 proven pattern, sz path deleted)
__global__ __launch_bounds__(256) void u_t_kernel(const u16* __restrict__ xi_re,
                                                  const float* __restrict__ cw,
                                                  const float* __restrict__ cb,
                                                  u16* __restrict__ ut,
                                                  u16* __restrict__ u_re) {
    __shared__ float xt[67][65];
    __shared__ u16 uo[64][70];
    int tid = threadIdx.x;
    int t0 = blockIdx.x * 64, e0 = blockIdx.y * 64, b = blockIdx.z;
    int er = tid & 63, rr = tid >> 6;
    for (int it = 0; it < 17; ++it) {
        int row = it * 4 + rr;
        if (row < 67) {
            int t = t0 + row - 3;
            xt[row][er] = (t >= 0) ? b2f(xi_re[((size_t)b * SEQ + t) * DINNER + e0 + er]) : 0.f;
        }
    }
    __syncthreads();
    {
        int e = tid & 63, tg = tid >> 6;
        float4 w4 = *(const float4*)(cw + (e0 + e) * 4);
        float cbe = cb[e0 + e];
        int tl0 = tg * 16;
        float x3 = xt[tl0][e], x2 = xt[tl0 + 1][e], x1 = xt[tl0 + 2][e];
        #pragma unroll
        for (int i = 0; i < 16; ++i) {
            float x0 = xt[tl0 + i + 3][e];
            float u = silu_f(cbe + w4.x * x3 + w4.y * x2 + w4.z * x1 + w4.w * x0);
            x3 = x2; x2 = x1; x1 = x0;
            u16 ub = f2b(u);
            uo[e][tl0 + i] = ub;
            u_re[((size_t)b * SEQ + t0 + tl0 + i) * DINNER + e0 + e] = ub;
        }
    }
    __syncthreads();
    {
        int tl = tid & 63, eg = tid >> 6;
        #pragma unroll
        for (int i = 0; i < 16; ++i) {
            int ee = eg * 16 + i;
            ut[((size_t)b * DINNER + e0 + ee) * SEQ + t0 + tl] = uo[ee][tl];
        }
    }
}

// ---------------------------------------------------------------- delta + B/C precompute (round-0 proven)
__global__ __launch_bounds__(256) void delta_bct_kernel(const float* __restrict__ dbc,
                                                        const float* __restrict__ dtw,
                                                        const float* __restrict__ dtb,
                                                        u16* __restrict__ dlt,
                                                        u16* __restrict__ Bt,
                                                        u16* __restrict__ Ct) {
    __shared__ float wl[64 * 32];
    __shared__ float bl[64];
    int tid = threadIdx.x;
    int e0 = blockIdx.x * 64, t0 = blockIdx.y * 256, b = blockIdx.z;
    for (int i = tid; i < 64 * 32; i += 256) wl[i] = dtw[(size_t)e0 * DTRANK + i];
    if (tid < 64) bl[tid] = dtb[e0 + tid];
    float dreg[32];
    const float* dp = dbc + (size_t)(b * SEQ + t0 + tid) * DBCW;
    #pragma unroll
    for (int k = 0; k < 32; k += 4) {
        float4 v = *(const float4*)(dp + k);
        dreg[k] = v.x; dreg[k + 1] = v.y; dreg[k + 2] = v.z; dreg[k + 3] = v.w;
    }
    __syncthreads();
    for (int ep = 0; ep < 64; ++ep) {
        float s = bl[ep];
        #pragma unroll
        for (int k = 0; k < 32; ++k) s += dreg[k] * wl[ep * 32 + k];
        dlt[((size_t)b * DINNER + e0 + ep) * SEQ + t0 + tid] = f2b(softplus_f(s));
    }
    if (blockIdx.x == 0) {
        int t = t0 + tid;
        const float* dp2 = dbc + (size_t)(b * SEQ + t) * DBCW + DTRANK;
        #pragma unroll
        for (int nn = 0; nn < DSTATE; ++nn) {
            Bt[((size_t)b * DSTATE + nn) * SEQ + t] = f2b(dp2[nn]);
            Ct[((size_t)b * DSTATE + nn) * SEQ + t] = f2b(dp2[DSTATE + nn]);
        }
    }
}

// ---------------------------------------------------------------- selective scan (round-4 pipelined version, unchanged)
#define SCHUNK 16

struct ChunkBuf {
    bf16x8 u0, u1, d0, d1, b0, b1, c0, c1;
    u16 uo_r, szo_r;
};

__global__ __launch_bounds__(256, 2) void scan_fused(u16* __restrict__ y_re,
                                                     const u16* __restrict__ ut,
                                                     const u16* __restrict__ dlt,
                                                     const u16* __restrict__ Bt,
                                                     const u16* __restrict__ Ct,
                                                     const u16* __restrict__ szt,
                                                     const float* __restrict__ Alog,
                                                     const float* __restrict__ Dp) {
    int tid = threadIdx.x;
    int pair = tid >> 4, n = tid & 15;
    int blk = blockIdx.x;
    int b = blk >> 6;
    int e = ((blk & 63) << 4) + pair;
    float a2 = -__expf(Alog[e * DSTATE + n]) * 1.44269504f;   // fold log2e: dA = exp2(dl*a2)
    float dpe = Dp[e];
    const u16* urow  = ut  + ((size_t)b * DINNER + e) * SEQ;
    const u16* dlrow = dlt + ((size_t)b * DINNER + e) * SEQ;
    const u16* szrow = szt + ((size_t)b * DINNER + e) * SEQ;
    const u16* Brow  = Bt + ((size_t)b * DSTATE + n) * SEQ;
    const u16* Crow  = Ct + ((size_t)b * DSTATE + n) * SEQ;
    // lane n stores t = c*16+n for its pair: scatter over 16 rows
    u16* ystore = y_re + ((size_t)b * SEQ + n) * DINNER + e;

    // per-lane 0/1 mask: lane n keeps time-step j==n of each chunk (1 fma/t)
    float msk[16];
    #pragma unroll
    for (int j = 0; j < 16; ++j) msk[j] = (n == j) ? 1.f : 0.f;

    float h = 0.f;
    ChunkBuf bufA, bufB, bufC, bufD;

    auto load = [&](int c, ChunkBuf& R) {
        R.u0 = *(const bf16x8*)(urow + c * SCHUNK);
        R.u1 = *(const bf16x8*)(urow + c * SCHUNK + 8);
        R.d0 = *(const bf16x8*)(dlrow + c * SCHUNK);
        R.d1 = *(const bf16x8*)(dlrow + c * SCHUNK + 8);
        R.b0 = *(const bf16x8*)(Brow + c * SCHUNK);
        R.b1 = *(const bf16x8*)(Brow + c * SCHUNK + 8);
        R.c0 = *(const bf16x8*)(Crow + c * SCHUNK);
        R.c1 = *(const bf16x8*)(Crow + c * SCHUNK + 8);
        R.uo_r  = urow[c * SCHUNK + n];    // lane n's own t (same cacheline as u0/u1)
        R.szo_r = szrow[c * SCHUNK + n];
    };
    auto proc = [&](int c, const ChunkBuf& R) {
        float keep = 0.f;
        #pragma unroll
        for (int j = 0; j < SCHUNK; ++j) {
            float uf = b2f((u16)((j < 8) ? R.u0[j] : R.u1[j - 8]));
            float dl = b2f((u16)((j < 8) ? R.d0[j] : R.d1[j - 8]));
            float dA = __builtin_amdgcn_exp2f(dl * a2);
            h = dA * h + (dl * uf) * b2f((u16)((j < 8) ? R.b0[j] : R.b1[j - 8]));
            float yp = sum16(h * b2f((u16)((j < 8) ? R.c0[j] : R.c1[j - 8])));
            keep += yp * msk[j];   // lane n keeps its own t's value
        }
        ystore[(size_t)c * SCHUNK * DINNER] =
            f2b((keep + b2f(R.uo_r) * dpe) * b2f(R.szo_r));
    };

    const int nc = SEQ / SCHUNK;   // 128, divisible by 4
    load(0, bufA);
    load(1, bufB);
    load(2, bufC);
    __builtin_amdgcn_sched_barrier(0);
    for (int c = 0; c < nc; c += 4) {
        int c3 = c + 3, c4 = c + 4, c5 = c + 5, c6 = c + 6;
        c4 = (c4 < nc) ? c4 : nc - 1;   // tail: redundant reloads of last chunk (cheap, branch-free)
        c5 = (c5 < nc) ? c5 : nc - 1;
        c6 = (c6 < nc) ? c6 : nc - 1;
        load(c3, bufD);  __builtin_amdgcn_sched_barrier(0);  proc(c,     bufA);
        load(c4, bufA);  __builtin_amdgcn_sched_barrier(0);  proc(c + 1, bufB);
        load(c5, bufB);  __builtin_amdgcn_sched_barrier(0);  proc(c + 2, bufC);
        load(c6, bufC);  __builtin_amdgcn_sched_barrier(0);  proc(c + 3, bufD);
    }
}

// ---------------------------------------------------------------- launch
extern "C" void kernel_launch(void* const* d_in, const int* in_sizes, int n_in,
                              void* d_out, int out_size, void* d_ws, size_t ws_size,
                              hipStream_t stream) {
    const float* x_in   = (const float*)d_in[0];
    const float* ln_w   = (const float*)d_in[1];
    const float* ln_b   = (const float*)d_in[2];
    const float* inw    = (const float*)d_in[3];
    const float* convw  = (const float*)d_in[4];
    const float* convb  = (const float*)d_in[5];
    const float* xpw    = (const float*)d_in[6];
    const float* dtw    = (const float*)d_in[7];
    const float* dtb    = (const float*)d_in[8];
    const float* Alog   = (const float*)d_in[9];
    const float* Dp     = (const float*)d_in[10];
    const float* outw   = (const float*)d_in[11];
    float* out = (float*)d_out;

    // workspace carve-up — identical proven footprint; sz_re region now unused
    // (gemm_in's z-half writes szt[b,e,t] directly).
    char* p = (char*)d_ws;
    u16* xi_re = (u16*)p;               p += (size_t)ROWS * DINNER * 2;          //  33,554,432
    u16* szre_unused = (u16*)p;         p += (size_t)ROWS * DINNER * 2;          //  33,554,432 (free)
    (void)szre_unused;
    u16* y_re  = (u16*)p;               p += (size_t)ROWS * DINNER * 2;          //  33,554,432
    float* dbc = (float*)p;             p += (size_t)ROWS * DBCW * 4;            //   4,194,304
    u16* dlt   = (u16*)p;               p += (size_t)B_SZ * DINNER * SEQ * 2;    //  33,554,432
    u16* u_re  = dlt;                   // alias: u_re consumed by gemm_xp before delta writes dlt
    u16* Bt    = (u16*)p;               p += (size_t)B_SZ * DSTATE * SEQ * 2;    //     524,288
    u16* xwbf  = Bt;                    // alias: xwbf consumed by gemm_xp before delta_bct writes Bt
    u16* Ct    = (u16*)p;               p += (size_t)B_SZ * DSTATE * SEQ * 2;    //     524,288
    u16* ut    = (u16*)p;               p += (size_t)B_SZ * DINNER * SEQ * 2;    //  33,554,432
    u16* xnbf  = ut;                    // alias: LN output (16.8 MB) dead before u_t writes ut
    u16* szt   = (u16*)p;               p += (size_t)B_SZ * DINNER * SEQ * 2;    //  33,554,432
    u16* inwbf = (u16*)p;               p += (size_t)N_INW * 2;                  //   4,194,304
    u16* outwbf = (u16*)p;              p += (size_t)N_OUTW * 2;                 //   2,097,152

    const dim3 blk256(256);
    const int n_conv = N_INW + N_OUTW + N_XW;

    for (int i = 0; i < DEPTH; ++i) {
        const float* x_cur = (i == 0) ? x_in : out;
        const float* lw  = ln_w  + (size_t)i * DMODEL;
        const float* lb  = ln_b  + (size_t)i * DMODEL;
        const float* iw  = inw   + (size_t)i * 2 * DINNER * DMODEL;
        const float* cw  = convw + (size_t)i * DINNER * DCONV;
        const float* cb  = convb + (size_t)i * DINNER;
        const float* xw  = xpw   + (size_t)i * DBCW * DINNER;
        const float* dw  = dtw   + (size_t)i * DINNER * DTRANK;
        const float* db  = dtb   + (size_t)i * DINNER;
        const float* Al  = Alog  + (size_t)i * DINNER * DSTATE;
        const float* Dpp = Dp    + (size_t)i * DINNER;
        const float* ow  = outw  + (size_t)i * DMODEL * DINNER;

        // 0. all weight conversions in one launch (xwbf parked in Bt region)
        conv_weights<<<(n_conv + 255) / 256, blk256, 0, stream>>>(
            iw, ow, xw, inwbf, outwbf, xwbf);
        // 1. LayerNorm -> bf16 (into ut region; dead before u_t writes)
        ln_kernel<<<ROWS, blk256, 0, stream>>>(x_cur, lw, lb, xnbf);
        // 2. in_proj (bf16 MFMA): xi_re row-major; szt[b,e,t] = silu(z) direct
        gemm_in<<<dim3(2 * DINNER / 128, ROWS / 128), blk256, 0, stream>>>(
            xnbf, inwbf, xi_re, szt);
        // 3. u precompute: ut[b,e,t] + u_re[r,e] (no sz path)
        u_t_kernel<<<dim3(SEQ / 64, DINNER / 64, B_SZ), blk256, 0, stream>>>(
            xi_re, cw, cb, ut, u_re);
        // 4. x_proj (bf16 MFMA, N=64): dbc = u_re @ xw^T
        gemm_xp_bf16<<<ROWS / 128, blk256, 0, stream>>>(u_re, xwbf, dbc);
        // 5. delta + B/C precompute (overwrites u_re/xwbf regions, now dead)
        delta_bct_kernel<<<dim3(DINNER / 64, SEQ / 256, B_SZ), blk256, 0, stream>>>(
            dbc, dw, db, dlt, Bt, Ct);
        // 6. scan + register-keep gated output: y_re bf16
        scan_fused<<<(B_SZ * DINNER) / 16, blk256, 0, stream>>>(
            y_re, ut, dlt, Bt, Ct, szt, Al, Dpp);
        // 7. out_proj (bf16 MFMA) + residual
        gemm_out<<<dim3(DMODEL / 128, ROWS / 128), blk256, 0, stream>>>(
            y_re, outwbf, x_cur, out);
    }
}